// Round 6
// baseline (281.071 us; speedup 1.0000x reference)
//
#include <hip/hip_runtime.h>
#include <math.h>

#define B_   64
#define L_   500
#define F_   256
#define H_   4
#define DK   64

typedef unsigned short u16;
typedef unsigned int   u32;
typedef __attribute__((ext_vector_type(8))) short short8;
typedef __attribute__((ext_vector_type(4))) float f32x4;

static __device__ __forceinline__ u16 f2bf(float f) {
    u32 u = __float_as_uint(f);
    u32 r = (u + 0x7FFFu + ((u >> 16) & 1u)) >> 16;
    return (u16)r;
}

// ---------------------------------------------------------------------------
// Prep: bf16 transposed weights + fused first-stage weight.
//  wvT/fcwT [256][256] ([n][k]); w2T[512][64] (n>=500 -> 0)
//  wfT[h][64 n][256 k] = (wq_h @ w1)^T  computed in fp32
// ---------------------------------------------------------------------------
__global__ __launch_bounds__(256) void prep_kernel(
    const float* __restrict__ wq, const float* __restrict__ wv,
    const float* __restrict__ fcw, const float* __restrict__ w1,
    const float* __restrict__ w2,
    u16* __restrict__ wvT, u16* __restrict__ fcwT,
    u16* __restrict__ w2T, u16* __restrict__ wfT)
{
    int t = blockIdx.x * 256 + threadIdx.x;
    int stride = gridDim.x * 256;
    for (int i = t; i < 256 * 256; i += stride) {
        int n = i >> 8, k = i & 255;
        wvT[i]  = f2bf(wv[k * 256 + n]);
        fcwT[i] = f2bf(fcw[k * 256 + n]);
    }
    for (int i = t; i < 512 * 64; i += stride) {
        int n = i >> 6, k = i & 63;
        w2T[i] = f2bf(n < 500 ? w2[k * 500 + n] : 0.f);
    }
    // wfT[((h*64+n)*256)+k] = sum_d wq[k*256 + h*64 + d] * w1[d*64 + n]
    for (int i = t; i < 4 * 64 * 256; i += stride) {
        int k = i & 255;
        int n = (i >> 8) & 63;
        int h = i >> 14;
        const float* wqp = wq + k * 256 + h * 64;
        float s = 0.f;
        #pragma unroll 8
        for (int d = 0; d < 64; d++)
            s = fmaf(wqp[d], w1[d * 64 + n], s);
        wfT[i] = f2bf(s);
    }
}

// ---------------------------------------------------------------------------
// Kernel 1: v head projection only, bf16 MFMA.
// grid (500), block 512 = 8 waves in 2x4; block tile 64 rows x 256 cols.
// out: vhT [bh][64 d][512 l] bf16 (l>=500 pad never written; P=0 there)
// ---------------------------------------------------------------------------
__global__ __launch_bounds__(512) void proj_kernel(
    const float* __restrict__ v, const u16* __restrict__ wvT,
    u16* __restrict__ vhT)
{
    __shared__ u16 Xs[64][72];    // [m][k], pad 144 B
    __shared__ u16 Ws[256][72];   // [n][k], pad 144 B

    const int tid  = threadIdx.x;
    const int wvid = tid >> 6, ln = tid & 63;
    const int n16  = ln & 15, quad = ln >> 4;
    const int wr   = wvid >> 2, wc = wvid & 3;   // 2 x 4
    const int row0 = blockIdx.x * 64;

    f32x4 acc[2][4];
    #pragma unroll
    for (int mt = 0; mt < 2; mt++)
        #pragma unroll
        for (int nt = 0; nt < 4; nt++) acc[mt][nt] = (f32x4){0.f, 0.f, 0.f, 0.f};

    for (int kc = 0; kc < 256; kc += 64) {
        // stage X (fp32 -> bf16): 64 x 64
        #pragma unroll
        for (int j = 0; j < 2; j++) {
            int idx = tid + 512 * j;
            int m = idx >> 4, k4 = idx & 15;
            float4 a = *(const float4*)&v[(size_t)(row0 + m) * 256 + kc + k4 * 4];
            __align__(8) u16 t4[4] = {f2bf(a.x), f2bf(a.y), f2bf(a.z), f2bf(a.w)};
            *(uint2*)&Xs[m][k4 * 4] = *(const uint2*)t4;
        }
        // stage W^T: 256 x 64 bf16
        #pragma unroll
        for (int j = 0; j < 4; j++) {
            int idx = tid + 512 * j;
            int n = idx >> 3, k8 = idx & 7;
            *(uint4*)&Ws[n][k8 * 8] = *(const uint4*)&wvT[n * 256 + kc + k8 * 8];
        }
        __syncthreads();
        #pragma unroll
        for (int ks = 0; ks < 2; ks++) {
            short8 af[2], bfr[4];
            #pragma unroll
            for (int mt = 0; mt < 2; mt++)
                af[mt] = *(const short8*)&Xs[wr * 32 + mt * 16 + n16][ks * 32 + quad * 8];
            #pragma unroll
            for (int nt = 0; nt < 4; nt++)
                bfr[nt] = *(const short8*)&Ws[wc * 64 + nt * 16 + n16][ks * 32 + quad * 8];
            #pragma unroll
            for (int mt = 0; mt < 2; mt++)
                #pragma unroll
                for (int nt = 0; nt < 4; nt++)
                    acc[mt][nt] = __builtin_amdgcn_mfma_f32_16x16x32_bf16(
                        af[mt], bfr[nt], acc[mt][nt], 0, 0, 0);
        }
        __syncthreads();
    }

    // epilogue: vhT[bh][d][l], h = wc, 4 consecutive l per lane -> uint2
    #pragma unroll
    for (int mt = 0; mt < 2; mt++) {
        int m0 = row0 + wr * 32 + mt * 16 + quad * 4;   // mult of 4, same b
        int b  = m0 / 500;
        int l0 = m0 - 500 * b;
        #pragma unroll
        for (int nt = 0; nt < 4; nt++) {
            int d = nt * 16 + n16;
            __align__(8) u16 t4[4];
            #pragma unroll
            for (int i = 0; i < 4; i++) t4[i] = f2bf(acc[mt][nt][i]);
            *(uint2*)&vhT[((size_t)((b * 4 + wc) * 64 + d)) * 512 + l0] =
                *(const uint2*)t4;
        }
    }
}

// ---------------------------------------------------------------------------
// Kernel 2: dense-synthesizer attention, bf16 MFMA, fused first projection:
//   s = relu(q @ wfused_h + b1), wfused_h = wq_h @ w1 (precomputed).
// grid (256 bh, 8 row-chunks) so same-bh blocks land on the same XCD.
// LDS: one 36 KB union region (s_tmp | w2 double-buffer | v+p) -> 4 blk/CU.
// ---------------------------------------------------------------------------
__global__ __launch_bounds__(256) void attn_kernel(
    const float* __restrict__ q, const u16* __restrict__ vhT,
    const u16* __restrict__ wfT, const float* __restrict__ b1,
    const u16* __restrict__ w2T, const float* __restrict__ b2,
    u16* __restrict__ ctx)
{
    __shared__ __align__(16) char lds_raw[36864];
    u16 (*s_tmp)[16][72]  = (u16 (*)[16][72])  lds_raw;             // [4][16][72]
    u16 (*w2s)[128][72]   = (u16 (*)[128][72]) lds_raw;             // [2][128][72]
    u16 (*v_lds)[136]     = (u16 (*)[136])     lds_raw;             // [64][136]
    u16 (*p_lds)[16][136] = (u16 (*)[16][136]) (lds_raw + 17408);   // [4][16][136]

    const int tid  = threadIdx.x;
    const int wv   = tid >> 6;
    const int ln   = tid & 63;
    const int n16  = ln & 15;
    const int quad = ln >> 4;
    const int bh   = blockIdx.x;
    const int b    = bh >> 2, h = bh & 3;
    const int r0   = blockIdx.y * 64 + wv * 16;

    // ---- Phase A: s = relu(q @ wfused_h + b1); q read direct (fp32->bf16) ----
    {
        int row = r0 + n16;
        if (row > 499) row = 499;               // clamp; dup rows discarded later
        const float* qp = q + ((size_t)b * 500 + row) * 256;
        short8 a[8];
        #pragma unroll
        for (int kt = 0; kt < 8; kt++) {
            float4 x0 = *(const float4*)(qp + kt * 32 + quad * 8);
            float4 x1 = *(const float4*)(qp + kt * 32 + quad * 8 + 4);
            short8 t;
            t[0] = (short)f2bf(x0.x); t[1] = (short)f2bf(x0.y);
            t[2] = (short)f2bf(x0.z); t[3] = (short)f2bf(x0.w);
            t[4] = (short)f2bf(x1.x); t[5] = (short)f2bf(x1.y);
            t[6] = (short)f2bf(x1.z); t[7] = (short)f2bf(x1.w);
            a[kt] = t;
        }
        const u16* wf = wfT + (size_t)h * 64 * 256;
        #pragma unroll
        for (int nt = 0; nt < 4; nt++) {
            f32x4 c = {0.f, 0.f, 0.f, 0.f};
            #pragma unroll
            for (int kt = 0; kt < 8; kt++) {
                short8 bb = *(const short8*)&wf[(nt * 16 + n16) * 256 + kt * 32 + quad * 8];
                c = __builtin_amdgcn_mfma_f32_16x16x32_bf16(a[kt], bb, c, 0, 0, 0);
            }
            float bias = b1[nt * 16 + n16];
            #pragma unroll
            for (int i = 0; i < 4; i++)
                s_tmp[wv][quad * 4 + i][nt * 16 + n16] = f2bf(fmaxf(c[i] + bias, 0.f));
        }
    }
    __syncthreads();
    short8 sa0 = *(const short8*)&s_tmp[wv][n16][quad * 8];
    short8 sa1 = *(const short8*)&s_tmp[wv][n16][32 + quad * 8];
    __syncthreads();   // s_tmp region about to be reused for w2 staging

    // ---- Phase B: logits = s @ w2 + b2; w2T staged in LDS, double-buffered ----
    f32x4 acc[32];
    {
        // stage chunk 0
        #pragma unroll
        for (int j = 0; j < 4; j++) {
            int idx = tid + 256 * j;
            int n = idx >> 3, k8 = idx & 7;
            *(uint4*)&w2s[0][n][k8 * 8] = *(const uint4*)&w2T[n * 64 + k8 * 8];
        }
        __syncthreads();
        for (int cc = 0; cc < 4; cc++) {
            if (cc < 3) {
                const u16* src = w2T + (cc + 1) * 128 * 64;
                #pragma unroll
                for (int j = 0; j < 4; j++) {
                    int idx = tid + 256 * j;
                    int n = idx >> 3, k8 = idx & 7;
                    *(uint4*)&w2s[(cc + 1) & 1][n][k8 * 8] =
                        *(const uint4*)&src[n * 64 + k8 * 8];
                }
            }
            u16 (*buf)[72] = w2s[cc & 1];
            #pragma unroll
            for (int t = 0; t < 8; t++) {
                int nt = cc * 8 + t;
                short8 bb0 = *(const short8*)&buf[t * 16 + n16][quad * 8];
                short8 bb1 = *(const short8*)&buf[t * 16 + n16][32 + quad * 8];
                f32x4 c = {0.f, 0.f, 0.f, 0.f};
                c = __builtin_amdgcn_mfma_f32_16x16x32_bf16(sa0, bb0, c, 0, 0, 0);
                c = __builtin_amdgcn_mfma_f32_16x16x32_bf16(sa1, bb1, c, 0, 0, 0);
                int col = nt * 16 + n16;
                float bias = (col < 500) ? b2[col] : -INFINITY;
                #pragma unroll
                for (int i = 0; i < 4; i++) c[i] += bias;
                acc[nt] = c;
            }
            __syncthreads();
        }
    }

    // ---- softmax stats (P unnormalized; fold 1/sum into epilogue) ----
    float inv[4];
    {
        float mx[4], sm[4];
        #pragma unroll
        for (int i = 0; i < 4; i++) mx[i] = acc[0][i];
        #pragma unroll
        for (int nt = 1; nt < 32; nt++)
            #pragma unroll
            for (int i = 0; i < 4; i++) mx[i] = fmaxf(mx[i], acc[nt][i]);
        #pragma unroll
        for (int off = 1; off < 16; off <<= 1)
            #pragma unroll
            for (int i = 0; i < 4; i++) mx[i] = fmaxf(mx[i], __shfl_xor(mx[i], off));
        #pragma unroll
        for (int i = 0; i < 4; i++) sm[i] = 0.f;
        #pragma unroll
        for (int nt = 0; nt < 32; nt++)
            #pragma unroll
            for (int i = 0; i < 4; i++) {
                float e = __expf(acc[nt][i] - mx[i]);
                acc[nt][i] = e;
                sm[i] += e;
            }
        #pragma unroll
        for (int off = 1; off < 16; off <<= 1)
            #pragma unroll
            for (int i = 0; i < 4; i++) sm[i] += __shfl_xor(sm[i], off);
        #pragma unroll
        for (int i = 0; i < 4; i++) inv[i] = 1.f / sm[i];
    }

    // ---- Phase C: out = P @ vh in 4 K-chunks of 128 ----
    f32x4 oacc[4];
    #pragma unroll
    for (int nt = 0; nt < 4; nt++) oacc[nt] = (f32x4){0.f, 0.f, 0.f, 0.f};

    for (int cc = 0; cc < 4; cc++) {
        #pragma unroll
        for (int u = tid; u < 1024; u += 256) {
            int d  = u >> 4;
            int kk = (u & 15) * 8;
            *(short8*)&v_lds[d][kk] =
                *(const short8*)(vhT + ((size_t)(bh * 64 + d)) * 512 + cc * 128 + kk);
        }
        #pragma unroll
        for (int t = 0; t < 8; t++) {
            int nt = cc * 8 + t;
            int c  = t * 16 + n16;
            #pragma unroll
            for (int i = 0; i < 4; i++)
                p_lds[wv][quad * 4 + i][c] = f2bf(acc[nt][i]);
        }
        __syncthreads();
        #pragma unroll
        for (int ks = 0; ks < 4; ks++) {
            short8 pa = *(const short8*)&p_lds[wv][n16][ks * 32 + quad * 8];
            #pragma unroll
            for (int nt = 0; nt < 4; nt++) {
                short8 vb = *(const short8*)&v_lds[nt * 16 + n16][ks * 32 + quad * 8];
                oacc[nt] = __builtin_amdgcn_mfma_f32_16x16x32_bf16(pa, vb, oacc[nt], 0, 0, 0);
            }
        }
        __syncthreads();
    }

    // ---- epilogue: scale, write ctx bf16 ----
    {
        #pragma unroll
        for (int i = 0; i < 4; i++) {
            int lrow = r0 + quad * 4 + i;
            if (lrow < 500) {
                float s = inv[i];
                u16* dst = &ctx[((size_t)(b * 500 + lrow)) * 256 + h * 64];
                #pragma unroll
                for (int nt = 0; nt < 4; nt++)
                    dst[nt * 16 + n16] = f2bf(oacc[nt][i] * s);
            }
        }
    }
}

// ---------------------------------------------------------------------------
// Kernel 3: out = LayerNorm(ctx @ fc_w + q), bf16 MFMA + fused LN epilogue.
// grid (500), block 512 = 8 waves in 2x4; block tile 64 rows x 256 cols.
// ---------------------------------------------------------------------------
__global__ __launch_bounds__(512) void final_kernel(
    const u16* __restrict__ ctx, const u16* __restrict__ fcwT,
    const float* __restrict__ qres, const float* __restrict__ g,
    const float* __restrict__ bta, float* __restrict__ out)
{
    __shared__ u16 Xs[64][72];
    __shared__ u16 Ws[256][72];
    __shared__ float red[4][2][64];   // [wc][s1|s2][row]
    __shared__ float murs[2][64];     // [mu|rs][row]

    const int tid  = threadIdx.x;
    const int wvid = tid >> 6, ln = tid & 63;
    const int n16  = ln & 15, quad = ln >> 4;
    const int wr   = wvid >> 2, wc = wvid & 3;   // 2 x 4
    const int row0 = blockIdx.x * 64;

    f32x4 acc[2][4];
    #pragma unroll
    for (int mt = 0; mt < 2; mt++)
        #pragma unroll
        for (int nt = 0; nt < 4; nt++) acc[mt][nt] = (f32x4){0.f, 0.f, 0.f, 0.f};

    for (int kc = 0; kc < 256; kc += 64) {
        // stage X: 64 x 64 bf16
        {
            int idx = tid;
            int m = idx >> 3, k8 = idx & 7;
            *(uint4*)&Xs[m][k8 * 8] =
                *(const uint4*)&ctx[(size_t)(row0 + m) * 256 + kc + k8 * 8];
        }
        // stage W^T: 256 x 64 bf16
        #pragma unroll
        for (int j = 0; j < 4; j++) {
            int idx = tid + 512 * j;
            int n = idx >> 3, k8 = idx & 7;
            *(uint4*)&Ws[n][k8 * 8] = *(const uint4*)&fcwT[n * 256 + kc + k8 * 8];
        }
        __syncthreads();
        #pragma unroll
        for (int ks = 0; ks < 2; ks++) {
            short8 af[2], bfr[4];
            #pragma unroll
            for (int mt = 0; mt < 2; mt++)
                af[mt] = *(const short8*)&Xs[wr * 32 + mt * 16 + n16][ks * 32 + quad * 8];
            #pragma unroll
            for (int nt = 0; nt < 4; nt++)
                bfr[nt] = *(const short8*)&Ws[wc * 64 + nt * 16 + n16][ks * 32 + quad * 8];
            #pragma unroll
            for (int mt = 0; mt < 2; mt++)
                #pragma unroll
                for (int nt = 0; nt < 4; nt++)
                    acc[mt][nt] = __builtin_amdgcn_mfma_f32_16x16x32_bf16(
                        af[mt], bfr[nt], acc[mt][nt], 0, 0, 0);
        }
        __syncthreads();
    }

    // residual add
    #pragma unroll
    for (int mt = 0; mt < 2; mt++) {
        int m0 = row0 + wr * 32 + mt * 16 + quad * 4;
        #pragma unroll
        for (int i = 0; i < 4; i++) {
            const float* rp = &qres[(size_t)(m0 + i) * 256 + wc * 64 + n16];
            #pragma unroll
            for (int nt = 0; nt < 4; nt++)
                acc[mt][nt][i] += rp[nt * 16];
        }
    }
    // per-row partial sums -> LDS
    #pragma unroll
    for (int mt = 0; mt < 2; mt++) {
        #pragma unroll
        for (int i = 0; i < 4; i++) {
            float s1 = 0.f, s2 = 0.f;
            #pragma unroll
            for (int nt = 0; nt < 4; nt++) {
                float vv = acc[mt][nt][i];
                s1 += vv; s2 += vv * vv;
            }
            #pragma unroll
            for (int off = 1; off < 16; off <<= 1) {
                s1 += __shfl_xor(s1, off);
                s2 += __shfl_xor(s2, off);
            }
            if (n16 == 0) {
                int r = wr * 32 + mt * 16 + quad * 4 + i;
                red[wc][0][r] = s1;
                red[wc][1][r] = s2;
            }
        }
    }
    __syncthreads();
    if (tid < 64) {
        float S1 = red[0][0][tid] + red[1][0][tid] + red[2][0][tid] + red[3][0][tid];
        float S2 = red[0][1][tid] + red[1][1][tid] + red[2][1][tid] + red[3][1][tid];
        float mu  = S1 * 0.00390625f;
        float var = S2 * 0.00390625f - mu * mu;
        murs[0][tid] = mu;
        murs[1][tid] = rsqrtf(var + 1e-6f);
    }
    __syncthreads();

    float gv[4], bv[4];
    #pragma unroll
    for (int nt = 0; nt < 4; nt++) {
        int col = wc * 64 + nt * 16 + n16;
        gv[nt] = g[col];
        bv[nt] = bta[col];
    }
    #pragma unroll
    for (int mt = 0; mt < 2; mt++) {
        int rb = wr * 32 + mt * 16 + quad * 4;
        #pragma unroll
        for (int i = 0; i < 4; i++) {
            float mu = murs[0][rb + i];
            float rs = murs[1][rb + i];
            float* op = &out[(size_t)(row0 + rb + i) * 256 + wc * 64 + n16];
            #pragma unroll
            for (int nt = 0; nt < 4; nt++)
                op[nt * 16] = (acc[mt][nt][i] - mu) * rs * gv[nt] + bv[nt];
        }
    }
}

// ---------------------------------------------------------------------------
extern "C" void kernel_launch(void* const* d_in, const int* in_sizes, int n_in,
                              void* d_out, int out_size, void* d_ws, size_t ws_size,
                              hipStream_t stream)
{
    const float* q   = (const float*)d_in[0];
    const float* v   = (const float*)d_in[2];
    const float* wqs = (const float*)d_in[3];
    const float* wvs = (const float*)d_in[4];
    const float* w1  = (const float*)d_in[5];
    const float* b1  = (const float*)d_in[6];
    const float* w2  = (const float*)d_in[7];
    const float* b2  = (const float*)d_in[8];
    const float* fcw = (const float*)d_in[9];
    const float* lng = (const float*)d_in[10];
    const float* lnb = (const float*)d_in[11];
    float* out = (float*)d_out;

    u16* vhT  = (u16*)d_ws;             // 256*64*512 = 8,388,608
    u16* w2T  = vhT + 8388608;          // 32,768
    u16* wvT  = w2T + 32768;            // 65,536
    u16* fcwT = wvT + 65536;            // 65,536
    u16* wfT  = fcwT + 65536;           // 65,536  (4 heads x 64 n x 256 k)
    u16* ctx  = wfT + 65536;            // 8,192,000

    prep_kernel <<<dim3(256),    256, 0, stream>>>(wqs, wvs, fcw, w1, w2,
                                                   wvT, fcwT, w2T, wfT);
    proj_kernel <<<dim3(500),    512, 0, stream>>>(v, wvT, vhT);
    attn_kernel <<<dim3(256, 8), 256, 0, stream>>>(q, vhT, wfT, b1, w2T, b2, ctx);
    final_kernel<<<dim3(500),    512, 0, stream>>>(ctx, fcwT, q, lng, lnb, out);
}